// Round 10
// baseline (281.731 us; speedup 1.0000x reference)
//
#include <hip/hip_runtime.h>

// MHA: fp32 in, fp32 out. B=2, S=2048, D=1024, H=16, dk=64. bf16 MFMA internals.
// ws 16MB: Kp[0,8) Vt[8,16) -> later O32[0,16).
// d_out 16MB: Qp/ctx[0,8), WqT/WkT/WvT/WoT bf16 [8,16).
// Attention v3: 256-thr blocks, 4 waves x 32q, 128k tiles. S^T = K*Q^T so the
// K A-frags amortize over 32 q-rows; P^T packs to b64 LDS writes; mask applied
// to V at the source (QKV gemm) and l computed via MFMA vs broadcast Ml.

typedef unsigned short u16;
typedef __attribute__((ext_vector_type(8))) short bf16x8;   // MFMA A/B frag (4 VGPR)
typedef __attribute__((ext_vector_type(4))) float f32x4;    // MFMA C/D frag

static __device__ __forceinline__ u16 f2bf(float x) {       // round-half-up
  union { float f; unsigned int i; } v; v.f = x;
  return (u16)((v.i + 0x8000u) >> 16);
}

#define MFMA_B16(a, b, c) __builtin_amdgcn_mfma_f32_16x16x32_bf16((a), (b), (c), 0, 0, 0)

// ---------------- prep: W fp32[K][N] -> Wt bf16[N][K], 4 weights -------------
__global__ __launch_bounds__(256) void prep_w(
    const float* __restrict__ w0, const float* __restrict__ w1,
    const float* __restrict__ w2, const float* __restrict__ w3,
    u16* __restrict__ t0, u16* __restrict__ t1,
    u16* __restrict__ t2, u16* __restrict__ t3) {
  __shared__ u16 tile[64 * 68];
  const float* W; u16* T;
  switch (blockIdx.z) {
    case 0: W = w0; T = t0; break;
    case 1: W = w1; T = t1; break;
    case 2: W = w2; T = t2; break;
    default: W = w3; T = t3; break;
  }
  const int t = threadIdx.x;
  const int k0 = blockIdx.x * 64, n0 = blockIdx.y * 64;
#pragma unroll
  for (int it = 0; it < 4; ++it) {
    int idx = it * 256 + t;
    int r = idx >> 4, c4 = idx & 15;
    float4 v = *(const float4*)&W[(size_t)(k0 + r) * 1024 + n0 + c4 * 4];
    tile[r * 68 + c4 * 4 + 0] = f2bf(v.x);
    tile[r * 68 + c4 * 4 + 1] = f2bf(v.y);
    tile[r * 68 + c4 * 4 + 2] = f2bf(v.z);
    tile[r * 68 + c4 * 4 + 3] = f2bf(v.w);
  }
  __syncthreads();
#pragma unroll
  for (int it = 0; it < 2; ++it) {
    int idx = it * 256 + t;
    int n = idx >> 3, kc = idx & 7;
    bf16x8 pk;
#pragma unroll
    for (int j = 0; j < 8; ++j) pk[j] = (short)tile[(kc * 8 + j) * 68 + n];
    *(bf16x8*)&T[(size_t)(n0 + n) * 1024 + k0 + kc * 8] = pk;
  }
}

// ---------------- GEMM, tile (MT*32)x128, BK=32, reg-staged prefetch ---------
// OMODE 3 region 2 (Vt scatter) applies the key-mask: masked keys write 0.
template <int MT, int AMODE, int OMODE>
__global__ __launch_bounds__(256) void gemm_bias(
    const void* a0v, const void* a1v, const void* a2v,
    const u16* __restrict__ Wt,
    const float* b0, const float* b1, const float* b2,
    void* o0, void* o1, void* o2, const int* msk) {
  __shared__ __align__(16) u16 As[MT * 32 * 32];
  __shared__ __align__(16) u16 Bs[128 * 32];
  const int t = threadIdx.x, wave = t >> 6, lane = t & 63;
  const int l15 = lane & 15, quad = lane >> 4;
  const int m0 = blockIdx.x * (MT * 32);
  const int n0 = blockIdx.y * 128;
  const int rg = (OMODE == 3) ? (n0 >> 10) : 0;
  const void* Av = (rg == 0) ? a0v : (rg == 1 ? a1v : a2v);
  const float* bp = (rg == 0) ? b0 : (rg == 1 ? b1 : b2);
  const int nb = (OMODE == 3) ? (n0 & 1023) : n0;
  const int wr = (wave >> 1) * (MT * 16), wc = (wave & 1) * 64;

  const f32x4 fz = {0.f, 0.f, 0.f, 0.f};
  f32x4 acc[MT][4];
#pragma unroll
  for (int mt = 0; mt < MT; ++mt)
#pragma unroll
    for (int nt = 0; nt < 4; ++nt) acc[mt][nt] = fz;

  float4 pa[MT / 2][2]; bf16x8 pab[MT / 2]; bf16x8 pb[2];
#pragma unroll
  for (int s = 0; s < MT / 2; ++s) {
    int idx = s * 256 + t, row = idx >> 2, seg = idx & 3;
    if (AMODE == 1) {
      const float* ap = (const float*)Av + (size_t)(m0 + row) * 1024 + seg * 8;
      pa[s][0] = *(const float4*)ap; pa[s][1] = *(const float4*)(ap + 4);
    } else {
      pab[s] = *(const bf16x8*)((const u16*)Av + (size_t)(m0 + row) * 1024 + seg * 8);
    }
  }
#pragma unroll
  for (int s = 0; s < 2; ++s) {
    int idx = s * 256 + t, row = idx >> 2, seg = idx & 3;
    pb[s] = *(const bf16x8*)&Wt[(size_t)(n0 + row) * 1024 + seg * 8];
  }

  for (int kb = 0; kb < 1024; kb += 32) {
    __syncthreads();
#pragma unroll
    for (int s = 0; s < MT / 2; ++s) {
      int idx = s * 256 + t, row = idx >> 2, seg = idx & 3;
      bf16x8 pk;
      if (AMODE == 1) {
        pk[0] = (short)f2bf(pa[s][0].x); pk[1] = (short)f2bf(pa[s][0].y);
        pk[2] = (short)f2bf(pa[s][0].z); pk[3] = (short)f2bf(pa[s][0].w);
        pk[4] = (short)f2bf(pa[s][1].x); pk[5] = (short)f2bf(pa[s][1].y);
        pk[6] = (short)f2bf(pa[s][1].z); pk[7] = (short)f2bf(pa[s][1].w);
      } else pk = pab[s];
      *(bf16x8*)&As[row * 32 + seg * 8] = pk;
    }
#pragma unroll
    for (int s = 0; s < 2; ++s) {
      int idx = s * 256 + t, row = idx >> 2, seg = idx & 3;
      *(bf16x8*)&Bs[row * 32 + seg * 8] = pb[s];
    }
    __syncthreads();
    const int kn = (kb + 32) & 1023;
#pragma unroll
    for (int s = 0; s < MT / 2; ++s) {
      int idx = s * 256 + t, row = idx >> 2, seg = idx & 3;
      if (AMODE == 1) {
        const float* ap = (const float*)Av + (size_t)(m0 + row) * 1024 + kn + seg * 8;
        pa[s][0] = *(const float4*)ap; pa[s][1] = *(const float4*)(ap + 4);
      } else {
        pab[s] = *(const bf16x8*)((const u16*)Av + (size_t)(m0 + row) * 1024 + kn + seg * 8);
      }
    }
#pragma unroll
    for (int s = 0; s < 2; ++s) {
      int idx = s * 256 + t, row = idx >> 2, seg = idx & 3;
      pb[s] = *(const bf16x8*)&Wt[(size_t)(n0 + row) * 1024 + kn + seg * 8];
    }
    bf16x8 a[MT], bfr[4];
#pragma unroll
    for (int mt = 0; mt < MT; ++mt)
      a[mt] = *(const bf16x8*)&As[(wr + mt * 16 + l15) * 32 + quad * 8];
#pragma unroll
    for (int nt = 0; nt < 4; ++nt)
      bfr[nt] = *(const bf16x8*)&Bs[(wc + nt * 16 + l15) * 32 + quad * 8];
#pragma unroll
    for (int mt = 0; mt < MT; ++mt)
#pragma unroll
      for (int nt = 0; nt < 4; ++nt)
        acc[mt][nt] = MFMA_B16(a[mt], bfr[nt], acc[mt][nt]);
  }

#pragma unroll
  for (int nt = 0; nt < 4; ++nt) {
    const int n = nb + wc + nt * 16 + l15;
    const float bv = bp[n];
#pragma unroll
    for (int mt = 0; mt < MT; ++mt)
#pragma unroll
      for (int r = 0; r < 4; ++r) {        // C/D: row=quad*4+r, col=l15
        const int m = m0 + wr + mt * 16 + quad * 4 + r;
        float val = acc[mt][nt][r] + bv;
        if (OMODE == 2) {
          ((float*)o0)[(size_t)m * 1024 + n] = val;
        } else if (OMODE == 0) {
          ((u16*)o0)[(size_t)m * 1024 + n] = f2bf(val);
        } else {
          if (rg == 0)      ((u16*)o0)[(size_t)m * 1024 + n] = f2bf(val);
          else if (rg == 1) ((u16*)o1)[(size_t)m * 1024 + n] = f2bf(val);
          else {
            const int h = n >> 6, d = n & 63, bb = m >> 11, ss = m & 2047;
            if (msk[bb * 2048 + ss]) val = 0.f;   // mask V rows at the source
            ((u16*)o2)[((size_t)(bb * 16 + h) * 64 + d) * 2048 + ss] = f2bf(val);
          }
        }
      }
  }
}

// ---------------- fused attention v3 -----------------------------------------
// grid (16 qtiles, 32 bh), 256 thr (4 waves x 32q). S^T = K*Q^T (C: col=q=l15,
// row=key=quad*4+r). P^T regs pack to ds_write_b64; PV reads Pl[q][key] b128.
// V pre-masked; l = P x Ml (broadcast 1/0 vector) via MFMA -> l lands per
// (quad*4+r), replicated over l15 — no shuffles at all.
__global__ __launch_bounds__(256) void attn_fused(
    const u16* Q, const u16* __restrict__ K,
    const u16* __restrict__ Vt, const int* __restrict__ mask,
    u16* ctx) {
  __shared__ __align__(16) u16 Ks[128 * 72];      // [key][dk]  18.0 KB
  __shared__ __align__(16) u16 Vs[64 * 136];      // [d][key]   17.0 KB
  __shared__ __align__(16) u16 Pl[4][32 * 136];   // [q][key]   34.0 KB
  __shared__ __align__(16) u16 Ml[2048];          // bf16 1.0 (keep) / 0.0 (masked)
  const int t = threadIdx.x, wave = t >> 6, lane = t & 63;
  const int l15 = lane & 15, quad = lane >> 4;
  const int bh = blockIdx.y, b = bh >> 4, h = bh & 15;
  const int q0 = blockIdx.x * 128 + wave * 32;
  const float cs = 0.125f * 1.44269504f;          // 1/sqrt(dk) * log2(e)

#pragma unroll
  for (int i = 0; i < 8; ++i) {                   // stage Ml once
    int idx = i * 256 + t;
    Ml[idx] = mask[b * 2048 + idx] ? 0 : 0x3F80;  // bf16 0.0 / 1.0
  }

  // Q B-frags: B[n=q=l15][k=dk=quad*8+j]; 2 q-halves x 2 dk-halves
  const u16* Qp = Q + (size_t)(b * 2048 + q0) * 1024 + h * 64;
  bf16x8 qf[2][2];
#pragma unroll
  for (int qh = 0; qh < 2; ++qh) {
    qf[qh][0] = *(const bf16x8*)(Qp + (size_t)(qh * 16 + l15) * 1024 + quad * 8);
    qf[qh][1] = *(const bf16x8*)(Qp + (size_t)(qh * 16 + l15) * 1024 + 32 + quad * 8);
  }

  const u16* Kbase = K + (size_t)(b * 2048) * 1024 + h * 64;   // + key*1024
  const u16* Vbase = Vt + (size_t)bh * 64 * 2048;              // + d*2048 + key

  // staging maps (256 thr, 4 slots each): K 128x64, V 64x128
  bf16x8 gk[4], gv[4];
#pragma unroll
  for (int s = 0; s < 4; ++s) {
    int ki = s * 256 + t, kr = ki >> 3, kc = (ki & 7) * 8;
    int vi = s * 256 + t, vr = vi >> 4, vc = (vi & 15) * 8;
    gk[s] = *(const bf16x8*)&Kbase[(size_t)kr * 1024 + kc];
    gv[s] = *(const bf16x8*)&Vbase[(size_t)vr * 2048 + vc];
  }

  const f32x4 fz = {0.f, 0.f, 0.f, 0.f};
  f32x4 o[2][4];              // O[qh][q=quad*4+r][d=nt*16+l15]
  f32x4 lacc[2];              // l[qh][q=quad*4+r], replicated over l15
#pragma unroll
  for (int qh = 0; qh < 2; ++qh) {
    lacc[qh] = fz;
#pragma unroll
    for (int nt = 0; nt < 4; ++nt) o[qh][nt] = fz;
  }

  for (int kt = 0; kt < 2048; kt += 128) {
    __syncthreads();                              // prev tile fully consumed
#pragma unroll
    for (int s = 0; s < 4; ++s) {                 // regs -> LDS
      int ki = s * 256 + t, kr = ki >> 3, kc = (ki & 7) * 8;
      int vi = s * 256 + t, vr = vi >> 4, vc = (vi & 15) * 8;
      *(bf16x8*)&Ks[kr * 72 + kc] = gk[s];
      *(bf16x8*)&Vs[vr * 136 + vc] = gv[s];
    }
    __syncthreads();
    const int kn = (kt + 128) & 2047;             // wrap: in-bounds, unused on last
#pragma unroll
    for (int s = 0; s < 4; ++s) {
      int ki = s * 256 + t, kr = ki >> 3, kc = (ki & 7) * 8;
      int vi = s * 256 + t, vr = vi >> 4, vc = (vi & 15) * 8;
      gk[s] = *(const bf16x8*)&Kbase[(size_t)(kn + kr) * 1024 + kc];
      gv[s] = *(const bf16x8*)&Vbase[(size_t)vr * 2048 + kn + vc];
    }

#pragma unroll
    for (int qh = 0; qh < 2; ++qh) {
      // S^T tiles: A=K frag [m=key][k=dk], B=Q frag -> C[key][q]
#pragma unroll
      for (int kb8 = 0; kb8 < 8; ++kb8) {
        const int krow = kb8 * 16 + l15;
        bf16x8 kf0 = *(const bf16x8*)&Ks[krow * 72 + quad * 8];
        bf16x8 kf1 = *(const bf16x8*)&Ks[krow * 72 + 32 + quad * 8];
        f32x4 st = MFMA_B16(kf0, qf[qh][0], fz);
        st = MFMA_B16(kf1, qf[qh][1], st);
        // p = exp2(s*cs); pack 4 consecutive keys (regs) -> one b64 write
        union { u16 h[4]; unsigned long long u; } pk;
#pragma unroll
        for (int r = 0; r < 4; ++r) pk.h[r] = f2bf(exp2f(st[r] * cs));
        *(unsigned long long*)&Pl[wave][(qh * 16 + l15) * 136 + kb8 * 16 + quad * 4] = pk.u;
      }
    }
    // O += P @ V ; l += P @ Ml (broadcast)
#pragma unroll
    for (int kc = 0; kc < 4; ++kc) {
      const bf16x8 mlf = *(const bf16x8*)&Ml[kt + kc * 32 + quad * 8];
#pragma unroll
      for (int qh = 0; qh < 2; ++qh) {
        const bf16x8 pf = *(const bf16x8*)&Pl[wave][(qh * 16 + l15) * 136 + kc * 32 + quad * 8];
        lacc[qh] = MFMA_B16(pf, mlf, lacc[qh]);
#pragma unroll
        for (int nt = 0; nt < 4; ++nt) {
          const bf16x8 vf = *(const bf16x8*)&Vs[(nt * 16 + l15) * 136 + kc * 32 + quad * 8];
          o[qh][nt] = MFMA_B16(pf, vf, o[qh][nt]);
        }
      }
    }
  }
  // epilogue: O/l; fully-masked rows (l==0) -> exact 0 (matches nan_to_num)
#pragma unroll
  for (int qh = 0; qh < 2; ++qh) {
    u16* cp = ctx + (size_t)(b * 2048 + q0 + qh * 16) * 1024 + h * 64;
#pragma unroll
    for (int r = 0; r < 4; ++r) {
      const bool ok = lacc[qh][r] > 0.f;
      const float inv = ok ? 1.f / lacc[qh][r] : 0.f;
#pragma unroll
      for (int nt = 0; nt < 4; ++nt)
        cp[(quad * 4 + r) * 1024 + nt * 16 + l15] = f2bf(ok ? o[qh][nt][r] * inv : 0.f);
    }
  }
}

// ---------------- host launch ------------------------------------------------
extern "C" void kernel_launch(void* const* d_in, const int* in_sizes, int n_in,
                              void* d_out, int out_size, void* d_ws, size_t ws_size,
                              hipStream_t stream) {
  const float* q    = (const float*)d_in[0];
  const float* k    = (const float*)d_in[1];
  const float* v    = (const float*)d_in[2];
  const int*   mask = (const int*)d_in[3];
  const float* Wq = (const float*)d_in[4];  const float* bq = (const float*)d_in[5];
  const float* Wk = (const float*)d_in[6];  const float* bk = (const float*)d_in[7];
  const float* Wv = (const float*)d_in[8];  const float* bv = (const float*)d_in[9];
  const float* Wo = (const float*)d_in[10]; const float* bo = (const float*)d_in[11];

  char* ws = (char*)d_ws;                       // 16 MB
  u16*   Kp  = (u16*)(ws + ((size_t)0 << 20));  // [4096][1024] bf16
  u16*   Vt  = (u16*)(ws + ((size_t)8 << 20));  // [32][64][2048] bf16 (pre-masked)
  float* O32 = (float*)ws;                      // [4096][1024] fp32 (after attn)

  char* od = (char*)d_out;                      // 16 MB
  u16* ctx = (u16*)od;                          // [0,8MB): Qp then ctx in-place
  u16* WqT = (u16*)(od + ((size_t)8 << 20));
  u16* WkT = (u16*)(od + ((size_t)10 << 20));
  u16* WvT = (u16*)(od + ((size_t)12 << 20));
  u16* WoT = (u16*)(od + ((size_t)14 << 20));

  dim3 blk(256);
  prep_w<<<dim3(16, 16, 4), blk, 0, stream>>>(Wq, Wk, Wv, Wo, WqT, WkT, WvT, WoT);
  gemm_bias<4, 1, 3><<<dim3(32, 24), blk, 0, stream>>>(
      q, k, v, WqT, bq, bk, bv, (void*)ctx, (void*)Kp, (void*)Vt, mask);
  attn_fused<<<dim3(16, 32), blk, 0, stream>>>(ctx, Kp, Vt, mask, ctx);
  gemm_bias<2, 0, 2><<<dim3(64, 8), blk, 0, stream>>>(
      ctx, nullptr, nullptr, WoT, bo, nullptr, nullptr, (void*)O32, nullptr, nullptr, mask);
  hipMemcpyAsync(d_out, O32, (size_t)out_size * sizeof(float),
                 hipMemcpyDeviceToDevice, stream);
}